// Round 14
// baseline (678.573 us; speedup 1.0000x reference)
//
#include <hip/hip_runtime.h>
#include <math.h>
#include <string.h>

#define NLAT 91
#define NLON 180
#define NCH  64
#define KSZ  25
#define NW   9
#define HALF 4
#define NB   2
#define NPK  16     // channel packs of 4
#define CGRP 4      // pack-groups (blocks over channel dim)
#define PPB  4      // packs per block
#define THREADS 192
#define XSCAP 2496  // float4 slots = 39936 B LDS (worst-case window ~2250)
#define PCAP  49152
#define CCAP  2048

// blob layout (host-built in ctor, one pinned H2D per call)
#define CLS_OFF   0                       // 91*31*4 = 11284
#define ROW_OFF   11520                   // 91*9*16 = 13104 -> ends 24624
#define PSIS_OFF  24832
#define BLOB_MAX  (PSIS_OFF + (size_t)PCAP * 16 + 64 + (size_t)PCAP * 4)

#ifndef M_PI
#define M_PI 3.14159265358979323846
#endif

typedef unsigned int u32;

// ---------------------------------------------------------------------------
// HOST (global ctor, outside graph capture): per-POINT class tables,
// bit-compatible with numpy (glibc libm, exact IEEE order, contraction off).
// Validated rounds 2-13 (absmax 1.5e-5). Point bucketed by (ring,sector)
// cell; <=4 nonzero psi_k in rings {ir,ir+1} x sectors {ip,ip+1}.
// ---------------------------------------------------------------------------
static int build_tables(unsigned char* blob, size_t* offs_off_out)
{
#pragma clang fp contract(off)
    int*   clsOff = (int*)(blob + CLS_OFF);
    int4*  rowi   = (int4*)(blob + ROW_OFF);
    float* psis   = (float*)(blob + PSIS_OFF);

    static double sth[NLAT], cth[NLAT], cphv[NLON], sphv[NLON];
    for (int t = 0; t < NLAT; t++) {
        double th = (M_PI * (double)t) / 90.0;
        sth[t] = sin(th); cth[t] = cos(th);
    }
    for (int q = 0; q < NLON; q++) {
        double ph = (2.0 * M_PI * (double)q) / 180.0;
        cphv[q] = cos(ph); sphv[q] = sin(ph);
    }
    const double cutoff = (4.0 * M_PI) / 90.0;
    const double dr     = cutoff / 4.0;
    const double dphi   = (2.0 * M_PI) / 6.0;

    static int   cw[30][CCAP];
    static int   cdq[30][CCAP];
    static float cps[30][CCAP][4];
    static int   ccnt[30];
    static u32   toffs[PCAP];

    int np = 0;
    for (int t = 0; t < NLAT; t++) {
        for (int c = 0; c < 30; c++) ccnt[c] = 0;
        int dqmin[NW], dqmax[NW];
        for (int w = 0; w < NW; w++) { dqmin[w] = 999; dqmax[w] = -999; }

        for (int w = 0; w < NW; w++) {
            int ti_raw = t - HALF + w;
            int valid = (ti_raw >= 0) && (ti_raw < NLAT);
            int ti = ti_raw < 0 ? 0 : (ti_raw > NLAT - 1 ? NLAT - 1 : ti_raw);
            for (int dq = -89; dq <= 90; dq++) {
                int q = dq < 0 ? dq + NLON : dq;
                double t1 = sth[t] * sth[ti];
                double t2 = t1 * cphv[q];
                double t3 = cth[t] * cth[ti];
                double zz = t2 + t3;
                if (zz > 1.0) zz = 1.0;
                if (zz < -1.0) zz = -1.0;
                double r = acos(zz);
                if (!(valid && (r <= cutoff))) continue;
                if (dq < dqmin[w]) dqmin[w] = dq;
                if (dq > dqmax[w]) dqmax[w] = dq;
                double xx = (cth[t] * sth[ti]) * cphv[q] - sth[t] * cth[ti];
                double yy = sth[ti] * sphv[q];
                double phi = atan2(yy, xx);
                { double m = fmod(phi, 2.0 * M_PI); if (m < 0.0) m += 2.0 * M_PI; phi = m; }
                double quad = sth[ti] * (M_PI / 90.0) * ((2.0 * M_PI) / 180.0);

                int ir = (int)floor(r / dr);  if (ir > 4) ir = 4; if (ir < 0) ir = 0;
                int ip = (int)floor(phi / dphi); if (ip > 5) ip = 5; if (ip < 0) ip = 0;
                int ip1 = (ip + 1) % 6;

                double angL, angH;
                {
                    double a = (phi - ip * dphi) + M_PI;
                    double m = fmod(a, 2.0 * M_PI); if (m < 0.0) m += 2.0 * M_PI;
                    double dp = fabs(m - M_PI);
                    angL = fmax(0.0, 1.0 - dp / dphi);
                }
                {
                    double a = (phi - ip1 * dphi) + M_PI;
                    double m = fmod(a, 2.0 * M_PI); if (m < 0.0) m += 2.0 * M_PI;
                    double dp = fabs(m - M_PI);
                    angH = fmax(0.0, 1.0 - dp / dphi);
                }
                float s0 = 0.f, s1 = 0.f, s2 = 0.f, s3 = 0.f;
                if (ir == 0) {
                    double rad0 = fmax(0.0, 1.0 - r / dr);
                    double rad1 = fmax(0.0, 1.0 - fabs(r - dr) / dr);
                    s0 = (float)(rad0 * quad);
                    s1 = (float)((rad1 * angL) * quad);
                    s2 = (float)((rad1 * angH) * quad);
                } else if (ir == 4) {
                    double rad4 = fmax(0.0, 1.0 - fabs(r - 4.0 * dr) / dr);
                    s0 = (float)((rad4 * angL) * quad);
                    s1 = (float)((rad4 * angH) * quad);
                } else {
                    double radL = fmax(0.0, 1.0 - fabs(r - ir * dr) / dr);
                    double radH = fmax(0.0, 1.0 - fabs(r - (ir + 1) * dr) / dr);
                    s0 = (float)((radL * angL) * quad);
                    s1 = (float)((radL * angH) * quad);
                    s2 = (float)((radH * angL) * quad);
                    s3 = (float)((radH * angH) * quad);
                }
                if (s0 == 0.f && s1 == 0.f && s2 == 0.f && s3 == 0.f) continue;
                int cls = ir * 6 + ip;
                int n = ccnt[cls];
                if (n < CCAP) {
                    cw[cls][n] = w; cdq[cls][n] = dq;
                    cps[cls][n][0] = s0; cps[cls][n][1] = s1;
                    cps[cls][n][2] = s2; cps[cls][n][3] = s3;
                    ccnt[cls] = n + 1;
                }
            }
        }
        int rb = 0, base[NW];
        for (int w = 0; w < NW; w++) {
            int len = (dqmin[w] <= dqmax[w]) ? (NLON + dqmax[w] - dqmin[w]) : 0;
            if (rb + len > XSCAP) len = XSCAP - rb;
            int tw = t - HALF + w;
            int ti = tw < 0 ? 0 : (tw > NLAT - 1 ? NLAT - 1 : tw);
            base[w] = rb;
            rowi[t * NW + w] = make_int4(rb, len, (dqmin[w] <= dqmax[w]) ? dqmin[w] : 0, ti);
            rb += len;
        }
        for (int cls = 0; cls < 30; cls++) {
            clsOff[t * 31 + cls] = np;
            for (int i = 0; i < ccnt[cls] && np < PCAP; i++) {
                int w = cw[cls][i], dq = cdq[cls][i];
                toffs[np] = (u32)(base[w] + (dq - rowi[t * NW + w].z));
                psis[4 * np + 0] = cps[cls][i][0];
                psis[4 * np + 1] = cps[cls][i][1];
                psis[4 * np + 2] = cps[cls][i][2];
                psis[4 * np + 3] = cps[cls][i][3];
                np++;
            }
        }
        clsOff[t * 31 + 30] = np;
    }
    size_t offs_off = (PSIS_OFF + (size_t)np * 16 + 63) & ~(size_t)63;
    memcpy(blob + offs_off, toffs, (size_t)np * 4);
    *offs_off_out = offs_off;
    return np;
}

struct GInit {
    unsigned char* blob;
    int np;
    size_t bytes, offs_off;
    GInit() {
        static unsigned char storage[BLOB_MAX];
        np = build_tables(storage, &offs_off);
        bytes = offs_off + (size_t)np * 4;
        unsigned char* p = nullptr;
        if (hipHostMalloc((void**)&p, bytes) == hipSuccess && p) {
            memcpy(p, storage, bytes);
            blob = p;
        } else {
            blob = storage;
        }
    }
};
static GInit g_init;

// ---------------------------------------------------------------------------
__global__ __launch_bounds__(192) void pack_x(const float* __restrict__ x,
                                              float4* __restrict__ xp4)
{
    int t = blockIdx.x, cp = blockIdx.y, b = blockIdx.z;
    int p = threadIdx.x;
    if (p >= NLON) return;
    int c0 = cp * 4;
    float4 v;
    v.x = x[((size_t)(b * NCH + c0 + 0) * NLAT + t) * NLON + p];
    v.y = x[((size_t)(b * NCH + c0 + 1) * NLAT + t) * NLON + p];
    v.z = x[((size_t)(b * NCH + c0 + 2) * NLAT + t) * NLON + p];
    v.w = x[((size_t)(b * NCH + c0 + 3) * NLAT + t) * NLON + p];
    xp4[((size_t)(b * NPK + cp) * NLAT + t) * NLON + p] = v;
}

__global__ void pack_w(const float* __restrict__ wgt, float4* __restrict__ wt2)
{
    int i = blockIdx.x * blockDim.x + threadIdx.x;
    if (i >= NPK * KSZ * NCH) return;
    int cp = i / (KSZ * NCH);
    int rem = i - cp * (KSZ * NCH);
    int k = rem / NCH;
    int o = rem - k * NCH;
    float4 v;
    v.x = wgt[((size_t)o * NCH + cp * 4 + 0) * KSZ + k];
    v.y = wgt[((size_t)o * NCH + cp * 4 + 1) * KSZ + k];
    v.z = wgt[((size_t)o * NCH + cp * 4 + 2) * KSZ + k];
    v.w = wgt[((size_t)o * NCH + cp * 4 + 3) * KSZ + k];
    wt2[i] = v;
}

// ---------------------------------------------------------------------------
// Per-class stage-1 body (compile-time z targets, rule-#20 safe).
// ---------------------------------------------------------------------------
template<int ROW, int IP>
__device__ __forceinline__ void runSeg(int sBeg, int sEnd,
    const u32* __restrict__ offsG, const float4* __restrict__ psisG,
    const float4* xs, int p,
    float (&z0)[4], float (&zA)[6][4], float (&zB)[6][4])
{
    constexpr int IP1 = (IP + 1) % 6;
#pragma unroll 2
    for (int s = sBeg; s < sEnd; ++s) {
        u32 off = offsG[s];
        float4 ps = psisG[s];
        float4 xv = xs[off + p];
        if (ROW == 0) {
            z0[0] = fmaf(ps.x, xv.x, z0[0]); z0[1] = fmaf(ps.x, xv.y, z0[1]);
            z0[2] = fmaf(ps.x, xv.z, z0[2]); z0[3] = fmaf(ps.x, xv.w, z0[3]);
            zB[IP][0] = fmaf(ps.y, xv.x, zB[IP][0]); zB[IP][1] = fmaf(ps.y, xv.y, zB[IP][1]);
            zB[IP][2] = fmaf(ps.y, xv.z, zB[IP][2]); zB[IP][3] = fmaf(ps.y, xv.w, zB[IP][3]);
            zB[IP1][0] = fmaf(ps.z, xv.x, zB[IP1][0]); zB[IP1][1] = fmaf(ps.z, xv.y, zB[IP1][1]);
            zB[IP1][2] = fmaf(ps.z, xv.z, zB[IP1][2]); zB[IP1][3] = fmaf(ps.z, xv.w, zB[IP1][3]);
        } else if (ROW == 4) {
            zA[IP][0] = fmaf(ps.x, xv.x, zA[IP][0]); zA[IP][1] = fmaf(ps.x, xv.y, zA[IP][1]);
            zA[IP][2] = fmaf(ps.x, xv.z, zA[IP][2]); zA[IP][3] = fmaf(ps.x, xv.w, zA[IP][3]);
            zA[IP1][0] = fmaf(ps.y, xv.x, zA[IP1][0]); zA[IP1][1] = fmaf(ps.y, xv.y, zA[IP1][1]);
            zA[IP1][2] = fmaf(ps.y, xv.z, zA[IP1][2]); zA[IP1][3] = fmaf(ps.y, xv.w, zA[IP1][3]);
        } else {
            zA[IP][0] = fmaf(ps.x, xv.x, zA[IP][0]); zA[IP][1] = fmaf(ps.x, xv.y, zA[IP][1]);
            zA[IP][2] = fmaf(ps.x, xv.z, zA[IP][2]); zA[IP][3] = fmaf(ps.x, xv.w, zA[IP][3]);
            zA[IP1][0] = fmaf(ps.y, xv.x, zA[IP1][0]); zA[IP1][1] = fmaf(ps.y, xv.y, zA[IP1][1]);
            zA[IP1][2] = fmaf(ps.y, xv.z, zA[IP1][2]); zA[IP1][3] = fmaf(ps.y, xv.w, zA[IP1][3]);
            zB[IP][0] = fmaf(ps.z, xv.x, zB[IP][0]); zB[IP][1] = fmaf(ps.z, xv.y, zB[IP][1]);
            zB[IP][2] = fmaf(ps.z, xv.z, zB[IP][2]); zB[IP][3] = fmaf(ps.z, xv.w, zB[IP][3]);
            zB[IP1][0] = fmaf(ps.w, xv.x, zB[IP1][0]); zB[IP1][1] = fmaf(ps.w, xv.y, zB[IP1][1]);
            zB[IP1][2] = fmaf(ps.w, xv.z, zB[IP1][2]); zB[IP1][3] = fmaf(ps.w, xv.w, zB[IP1][3]);
        }
    }
}

// ---------------------------------------------------------------------------
// Compact stage-2 flush: runtime j-loop (unroll DISABLED -> ~3KB of code
// executed 6x, fixing r13's 60KB+ I-cache stream), switch selects the ring's
// z quad into registers; acc indices stay compile-time static.
// ---------------------------------------------------------------------------
__device__ __forceinline__ void flushRingLoop(float (&acc)[NCH],
    const float4* __restrict__ wt2cp, int kbase, const float (&zR)[6][4])
{
#pragma clang loop unroll(disable)
    for (int j = 0; j < 6; j++) {
        float zc0, zc1, zc2, zc3;
        switch (j) {
            case 0:  zc0 = zR[0][0]; zc1 = zR[0][1]; zc2 = zR[0][2]; zc3 = zR[0][3]; break;
            case 1:  zc0 = zR[1][0]; zc1 = zR[1][1]; zc2 = zR[1][2]; zc3 = zR[1][3]; break;
            case 2:  zc0 = zR[2][0]; zc1 = zR[2][1]; zc2 = zR[2][2]; zc3 = zR[2][3]; break;
            case 3:  zc0 = zR[3][0]; zc1 = zR[3][1]; zc2 = zR[3][2]; zc3 = zR[3][3]; break;
            case 4:  zc0 = zR[4][0]; zc1 = zR[4][1]; zc2 = zR[4][2]; zc3 = zR[4][3]; break;
            default: zc0 = zR[5][0]; zc1 = zR[5][1]; zc2 = zR[5][2]; zc3 = zR[5][3]; break;
        }
        const float4* wk = wt2cp + (size_t)(kbase + j) * NCH;
#pragma unroll
        for (int o = 0; o < NCH; o++) {
            float4 w4 = wk[o];
            acc[o] = fmaf(w4.w, zc3, fmaf(w4.z, zc2,
                     fmaf(w4.y, zc1, fmaf(w4.x, zc0, acc[o]))));
        }
    }
}

// ---------------------------------------------------------------------------
// Main fused kernel. Block = (t, pack-group of 4, b); thread owns p.
// Per pack: stage jagged window, ring walk (per-point classes), compact
// per-ring flush into acc[64] (accumulated over the 4 packs).
// Epilogue: plain coalesced stores to partial slab [cg][b][o][t][p].
// ---------------------------------------------------------------------------
__global__ __launch_bounds__(THREADS, 3) void disco_fused(
    const float4* __restrict__ xp4, const float4* __restrict__ wt2,
    const u32* __restrict__ offsG, const float4* __restrict__ psisG,
    const int* __restrict__ clsOffG, const int4* __restrict__ rowG,
    float* __restrict__ part)
{
    int t = blockIdx.x, cg = blockIdx.y, b = blockIdx.z;
    int tid = threadIdx.x;
    int p = tid < NLON ? tid : NLON - 1;
    bool act = tid < NLON;

    __shared__ float4 xs[XSCAP];    // 39936 B
    const int* co = clsOffG + t * 31;

    float acc[NCH];
#pragma unroll
    for (int o = 0; o < NCH; o++) acc[o] = 0.f;

    for (int pk = 0; pk < PPB; pk++) {
        int cp = cg * PPB + pk;
        __syncthreads();
#pragma unroll
        for (int w = 0; w < NW; w++) {
            int4 ri = rowG[t * NW + w];             // {base, len, dqmin, ti}
            const float4* src = xp4 + ((size_t)(b * NPK + cp) * NLAT + ri.w) * NLON;
            for (int j = tid; j < ri.y; j += THREADS) {
                int s = j + ri.z;
                if (s < 0) s += NLON;
                if (s >= NLON) s -= NLON;
                xs[ri.x + j] = src[s];
            }
        }
        __syncthreads();

        const float4* wt2cp = wt2 + (size_t)cp * KSZ * NCH;

        float z0[4] = {0.f, 0.f, 0.f, 0.f};
        float zA[6][4], zB[6][4];
#pragma unroll
        for (int j = 0; j < 6; j++)
#pragma unroll
            for (int c = 0; c < 4; c++) { zA[j][c] = 0.f; zB[j][c] = 0.f; }

#define SEG(ROW, IP) runSeg<ROW, IP>(co[(ROW)*6+(IP)], co[(ROW)*6+(IP)+1], \
                                     offsG, psisG, xs, p, z0, zA, zB)
#define ROW6(ROW) SEG(ROW,0); SEG(ROW,1); SEG(ROW,2); SEG(ROW,3); SEG(ROW,4); SEG(ROW,5)
#define ROLL() { _Pragma("unroll") for (int j = 0; j < 6; j++) { \
                 _Pragma("unroll") for (int c = 0; c < 4; c++) { \
                   zA[j][c] = zB[j][c]; zB[j][c] = 0.f; } } }

        ROW6(0);
        {   // flush k=0 from z0 (single k: compact, executed once per pack)
            const float4* wk = wt2cp;
#pragma unroll
            for (int o = 0; o < NCH; o++) {
                float4 w4 = wk[o];
                acc[o] = fmaf(w4.w, z0[3], fmaf(w4.z, z0[2],
                         fmaf(w4.y, z0[1], fmaf(w4.x, z0[0], acc[o]))));
            }
        }
        ROLL();
        ROW6(1);
        flushRingLoop(acc, wt2cp, 1, zA);    // k 1..6
        ROLL();
        ROW6(2);
        flushRingLoop(acc, wt2cp, 7, zA);    // k 7..12
        ROLL();
        ROW6(3);
        flushRingLoop(acc, wt2cp, 13, zA);   // k 13..18
        ROLL();
        ROW6(4);
        flushRingLoop(acc, wt2cp, 19, zA);   // k 19..24
#undef SEG
#undef ROW6
#undef ROLL
    }

    if (act) {
        float* dst = part + ((((size_t)cg * NB + b) * NCH) * NLAT + t) * NLON + p;
#pragma unroll
        for (int o = 0; o < NCH; o++)
            dst[(size_t)o * (NLAT * NLON)] = acc[o];
    }
}

// ---------------------------------------------------------------------------
// Sum the 4 pack-group partials into d_out.
// ---------------------------------------------------------------------------
__global__ void reduce_part(const float* __restrict__ part,
                            float* __restrict__ out, int n4)
{
    int i = blockIdx.x * blockDim.x + threadIdx.x;
    if (i >= n4) return;
    const float4* p4 = (const float4*)part;
    float4 a = p4[i];
    float4 b = p4[i + (size_t)n4];
    float4 c = p4[i + 2 * (size_t)n4];
    float4 d = p4[i + 3 * (size_t)n4];
    float4 r;
    r.x = a.x + b.x + c.x + d.x;
    r.y = a.y + b.y + c.y + d.y;
    r.z = a.z + b.z + c.z + d.z;
    r.w = a.w + b.w + c.w + d.w;
    ((float4*)out)[i] = r;
}

extern "C" void kernel_launch(void* const* d_in, const int* in_sizes, int n_in,
                              void* d_out, int out_size, void* d_ws, size_t ws_size,
                              hipStream_t stream)
{
    const float* x   = (const float*)d_in[0];
    const float* wgt = (const float*)d_in[1];
    char* ws = (char*)d_ws;

    size_t cur = 0;
    auto alloc = [&](size_t bytes) { size_t o = cur; cur = (cur + bytes + 255) & ~(size_t)255; return o; };
    size_t blob_off = alloc(BLOB_MAX);                                 // ~0.85 MB
    size_t xp4_off  = alloc((size_t)NB * NPK * NLAT * NLON * 16);      // 8.4 MB
    size_t wt2_off  = alloc((size_t)NPK * KSZ * NCH * 16);             // 400 KB
    size_t part_off = alloc((size_t)CGRP * NB * NCH * NLAT * NLON * 4);// 33.5 MB

    unsigned char* d_blob = (unsigned char*)(ws + blob_off);
    float4*        xp4    = (float4*)(ws + xp4_off);
    float4*        wt2    = (float4*)(ws + wt2_off);
    float*         part   = (float*)(ws + part_off);

    hipMemcpyAsync(d_blob, g_init.blob, g_init.bytes, hipMemcpyHostToDevice, stream);
    pack_x<<<dim3(NLAT, NPK, NB), 192, 0, stream>>>(x, xp4);
    pack_w<<<(NPK * KSZ * NCH + 255) / 256, 256, 0, stream>>>(wgt, wt2);

    const u32*    offsD = (const u32*)(d_blob + g_init.offs_off);
    const float4* psisD = (const float4*)(d_blob + PSIS_OFF);
    const int*    clsD  = (const int*)(d_blob + CLS_OFF);
    const int4*   rowD  = (const int4*)(d_blob + ROW_OFF);

    disco_fused<<<dim3(NLAT, CGRP, NB), THREADS, 0, stream>>>(
        xp4, wt2, offsD, psisD, clsD, rowD, part);

    int n  = NB * NCH * NLAT * NLON;   // 2,096,640
    int n4 = n / 4;
    reduce_part<<<(n4 + 255) / 256, 256, 0, stream>>>(part, (float*)d_out, n4);
}

// Round 15
// 487.925 us; speedup vs baseline: 1.3907x; 1.3907x over previous
//
#include <hip/hip_runtime.h>
#include <math.h>
#include <string.h>

#define NLAT 91
#define NLON 180
#define NCH  64
#define KSZ  25
#define NW   9
#define HALF 4
#define NB   2
#define NP2  32     // channel packs of 2
#define CGRP 16     // blocks over channel dim
#define PPB  2      // packs per block
#define THREADS 192
#define PCAP  49152
#define CCAP  2048

// blob layout (host-built in ctor, one pinned H2D per call)
#define CLS_OFF   0                       // 91*31*4 = 11284
#define PSIS_OFF  11520                   // float4 * np
#define BLOB_MAX  (PSIS_OFF + (size_t)PCAP * 16 + 64 + (size_t)PCAP * 4)

#ifndef M_PI
#define M_PI 3.14159265358979323846
#endif

typedef unsigned int u32;

// ---------------------------------------------------------------------------
// HOST (global ctor, outside graph capture): per-POINT class tables,
// bit-compatible with numpy (glibc libm, exact IEEE order, contraction off).
// Validated rounds 2-14 (absmax 1.5e-5). Point bucketed by (ring,sector)
// cell; <=4 nonzero psi_k live in rings {ir,ir+1} x sectors {ip,ip+1}.
// Offset is ABSOLUTE: off = ti*360 + dq + 90 into the doubled x rows.
// ---------------------------------------------------------------------------
static int build_tables(unsigned char* blob, size_t* offs_off_out)
{
#pragma clang fp contract(off)
    int*   clsOff = (int*)(blob + CLS_OFF);
    float* psis   = (float*)(blob + PSIS_OFF);

    static double sth[NLAT], cth[NLAT], cphv[NLON], sphv[NLON];
    for (int t = 0; t < NLAT; t++) {
        double th = (M_PI * (double)t) / 90.0;
        sth[t] = sin(th); cth[t] = cos(th);
    }
    for (int q = 0; q < NLON; q++) {
        double ph = (2.0 * M_PI * (double)q) / 180.0;
        cphv[q] = cos(ph); sphv[q] = sin(ph);
    }
    const double cutoff = (4.0 * M_PI) / 90.0;
    const double dr     = cutoff / 4.0;
    const double dphi   = (2.0 * M_PI) / 6.0;

    static u32   coff[30][CCAP];
    static float cps[30][CCAP][4];
    static int   ccnt[30];
    static u32   toffs[PCAP];

    int np = 0;
    for (int t = 0; t < NLAT; t++) {
        for (int c = 0; c < 30; c++) ccnt[c] = 0;

        for (int w = 0; w < NW; w++) {
            int ti_raw = t - HALF + w;
            int valid = (ti_raw >= 0) && (ti_raw < NLAT);
            int ti = ti_raw < 0 ? 0 : (ti_raw > NLAT - 1 ? NLAT - 1 : ti_raw);
            for (int dq = -89; dq <= 90; dq++) {
                int q = dq < 0 ? dq + NLON : dq;
                double t1 = sth[t] * sth[ti];
                double t2 = t1 * cphv[q];
                double t3 = cth[t] * cth[ti];
                double zz = t2 + t3;
                if (zz > 1.0) zz = 1.0;
                if (zz < -1.0) zz = -1.0;
                double r = acos(zz);
                if (!(valid && (r <= cutoff))) continue;
                double xx = (cth[t] * sth[ti]) * cphv[q] - sth[t] * cth[ti];
                double yy = sth[ti] * sphv[q];
                double phi = atan2(yy, xx);
                { double m = fmod(phi, 2.0 * M_PI); if (m < 0.0) m += 2.0 * M_PI; phi = m; }
                double quad = sth[ti] * (M_PI / 90.0) * ((2.0 * M_PI) / 180.0);

                int ir = (int)floor(r / dr);  if (ir > 4) ir = 4; if (ir < 0) ir = 0;
                int ip = (int)floor(phi / dphi); if (ip > 5) ip = 5; if (ip < 0) ip = 0;
                int ip1 = (ip + 1) % 6;

                double angL, angH;
                {
                    double a = (phi - ip * dphi) + M_PI;
                    double m = fmod(a, 2.0 * M_PI); if (m < 0.0) m += 2.0 * M_PI;
                    double dp = fabs(m - M_PI);
                    angL = fmax(0.0, 1.0 - dp / dphi);
                }
                {
                    double a = (phi - ip1 * dphi) + M_PI;
                    double m = fmod(a, 2.0 * M_PI); if (m < 0.0) m += 2.0 * M_PI;
                    double dp = fabs(m - M_PI);
                    angH = fmax(0.0, 1.0 - dp / dphi);
                }
                float s0 = 0.f, s1 = 0.f, s2 = 0.f, s3 = 0.f;
                if (ir == 0) {
                    double rad0 = fmax(0.0, 1.0 - r / dr);
                    double rad1 = fmax(0.0, 1.0 - fabs(r - dr) / dr);
                    s0 = (float)(rad0 * quad);
                    s1 = (float)((rad1 * angL) * quad);
                    s2 = (float)((rad1 * angH) * quad);
                } else if (ir == 4) {
                    double rad4 = fmax(0.0, 1.0 - fabs(r - 4.0 * dr) / dr);
                    s0 = (float)((rad4 * angL) * quad);
                    s1 = (float)((rad4 * angH) * quad);
                } else {
                    double radL = fmax(0.0, 1.0 - fabs(r - ir * dr) / dr);
                    double radH = fmax(0.0, 1.0 - fabs(r - (ir + 1) * dr) / dr);
                    s0 = (float)((radL * angL) * quad);
                    s1 = (float)((radL * angH) * quad);
                    s2 = (float)((radH * angL) * quad);
                    s3 = (float)((radH * angH) * quad);
                }
                if (s0 == 0.f && s1 == 0.f && s2 == 0.f && s3 == 0.f) continue;
                int cls = ir * 6 + ip;
                int n = ccnt[cls];
                if (n < CCAP) {
                    coff[cls][n] = (u32)(ti * 360 + dq + 90);   // absolute doubled-row offset
                    cps[cls][n][0] = s0; cps[cls][n][1] = s1;
                    cps[cls][n][2] = s2; cps[cls][n][3] = s3;
                    ccnt[cls] = n + 1;
                }
            }
        }
        for (int cls = 0; cls < 30; cls++) {
            clsOff[t * 31 + cls] = np;
            for (int i = 0; i < ccnt[cls] && np < PCAP; i++) {
                toffs[np] = coff[cls][i];
                psis[4 * np + 0] = cps[cls][i][0];
                psis[4 * np + 1] = cps[cls][i][1];
                psis[4 * np + 2] = cps[cls][i][2];
                psis[4 * np + 3] = cps[cls][i][3];
                np++;
            }
        }
        clsOff[t * 31 + 30] = np;
    }
    size_t offs_off = (PSIS_OFF + (size_t)np * 16 + 63) & ~(size_t)63;
    memcpy(blob + offs_off, toffs, (size_t)np * 4);
    *offs_off_out = offs_off;
    return np;
}

struct GInit {
    unsigned char* blob;
    int np;
    size_t bytes, offs_off;
    GInit() {
        static unsigned char storage[BLOB_MAX];
        np = build_tables(storage, &offs_off);
        bytes = offs_off + (size_t)np * 4;
        unsigned char* p = nullptr;
        if (hipHostMalloc((void**)&p, bytes) == hipSuccess && p) {
            memcpy(p, storage, bytes);
            blob = p;
        } else {
            blob = storage;
        }
    }
};
static GInit g_init;

// ---------------------------------------------------------------------------
// pack x [b][c][t][p] -> doubled 2-channel rows:
// xd2[((b*32+cp2)*91+t)*360 + u] = {x[b][2cp2][t][(u+90)%180], x[b][2cp2+1][...]}
// ---------------------------------------------------------------------------
__global__ __launch_bounds__(THREADS) void pack_x2(const float* __restrict__ x,
                                                   float2* __restrict__ xd)
{
    int t = blockIdx.x, cp2 = blockIdx.y, b = blockIdx.z;
    const float* x0 = x + ((size_t)(b * NCH + cp2 * 2) * NLAT + t) * NLON;
    const float* x1 = x0 + (size_t)NLAT * NLON;
    float2* dst = xd + ((size_t)(b * NP2 + cp2) * NLAT + t) * 360;
    for (int u = threadIdx.x; u < 360; u += THREADS) {
        int s = u + 90;
        if (s >= NLON) s -= NLON;
        if (s >= NLON) s -= NLON;
        dst[u] = make_float2(x0[s], x1[s]);
    }
}

// ---------------------------------------------------------------------------
// weights [o][c][k] -> wt2[(cp2*25+k)*64+o] float2 over the pack's 2 c.
// ---------------------------------------------------------------------------
__global__ void pack_w2(const float* __restrict__ wgt, float2* __restrict__ wt2)
{
    int i = blockIdx.x * blockDim.x + threadIdx.x;
    if (i >= NP2 * KSZ * NCH) return;
    int cp2 = i / (KSZ * NCH);
    int rem = i - cp2 * (KSZ * NCH);
    int k = rem / NCH;
    int o = rem - k * NCH;
    float2 v;
    v.x = wgt[((size_t)o * NCH + cp2 * 2 + 0) * KSZ + k];
    v.y = wgt[((size_t)o * NCH + cp2 * 2 + 1) * KSZ + k];
    wt2[i] = v;
}

// ---------------------------------------------------------------------------
// Per-class stage-1 body (compile-time z targets). Per point: 2 s_loads +
// 1 coalesced global float2 load (vmcnt, L2-resident) + 4-8 FMA.
// ---------------------------------------------------------------------------
template<int ROW, int IP>
__device__ __forceinline__ void runSeg2(int sBeg, int sEnd,
    const u32* __restrict__ offsG, const float4* __restrict__ psisG,
    const float2* __restrict__ xgb, int p,
    float (&z0)[2], float (&zA)[6][2], float (&zB)[6][2])
{
    constexpr int IP1 = (IP + 1) % 6;
#pragma unroll 2
    for (int s = sBeg; s < sEnd; ++s) {
        u32 off = offsG[s];
        float4 ps = psisG[s];
        float2 xv = xgb[off + p];
        if (ROW == 0) {
            z0[0] = fmaf(ps.x, xv.x, z0[0]);  z0[1] = fmaf(ps.x, xv.y, z0[1]);
            zB[IP][0] = fmaf(ps.y, xv.x, zB[IP][0]);   zB[IP][1] = fmaf(ps.y, xv.y, zB[IP][1]);
            zB[IP1][0] = fmaf(ps.z, xv.x, zB[IP1][0]); zB[IP1][1] = fmaf(ps.z, xv.y, zB[IP1][1]);
        } else if (ROW == 4) {
            zA[IP][0] = fmaf(ps.x, xv.x, zA[IP][0]);   zA[IP][1] = fmaf(ps.x, xv.y, zA[IP][1]);
            zA[IP1][0] = fmaf(ps.y, xv.x, zA[IP1][0]); zA[IP1][1] = fmaf(ps.y, xv.y, zA[IP1][1]);
        } else {
            zA[IP][0] = fmaf(ps.x, xv.x, zA[IP][0]);   zA[IP][1] = fmaf(ps.x, xv.y, zA[IP][1]);
            zA[IP1][0] = fmaf(ps.y, xv.x, zA[IP1][0]); zA[IP1][1] = fmaf(ps.y, xv.y, zA[IP1][1]);
            zB[IP][0] = fmaf(ps.z, xv.x, zB[IP][0]);   zB[IP][1] = fmaf(ps.z, xv.y, zB[IP][1]);
            zB[IP1][0] = fmaf(ps.w, xv.x, zB[IP1][0]); zB[IP1][1] = fmaf(ps.w, xv.y, zB[IP1][1]);
        }
    }
}

// ---------------------------------------------------------------------------
// Compact stage-2 flush (runtime j-loop, switch keeps z in registers).
// ---------------------------------------------------------------------------
__device__ __forceinline__ void flushRing2(float (&acc)[NCH],
    const float2* __restrict__ wt2cp, int kbase, const float (&zR)[6][2])
{
#pragma clang loop unroll(disable)
    for (int j = 0; j < 6; j++) {
        float zc0, zc1;
        switch (j) {
            case 0:  zc0 = zR[0][0]; zc1 = zR[0][1]; break;
            case 1:  zc0 = zR[1][0]; zc1 = zR[1][1]; break;
            case 2:  zc0 = zR[2][0]; zc1 = zR[2][1]; break;
            case 3:  zc0 = zR[3][0]; zc1 = zR[3][1]; break;
            case 4:  zc0 = zR[4][0]; zc1 = zR[4][1]; break;
            default: zc0 = zR[5][0]; zc1 = zR[5][1]; break;
        }
        const float2* wk = wt2cp + (size_t)(kbase + j) * NCH;
#pragma unroll
        for (int o = 0; o < NCH; o++) {
            float2 w2 = wk[o];
            acc[o] = fmaf(w2.y, zc1, fmaf(w2.x, zc0, acc[o]));
        }
    }
}

// ---------------------------------------------------------------------------
// Main fused kernel. Block = (t, cg of 2 packs, b); thread owns p. NO LDS:
// x gathers are coalesced per-lane global float2 loads from the doubled,
// L2-resident xd2. Ring walk with rolling 2-ring z (26 regs) + acc[64] in
// VGPRs (PACK2 keeps footprint ~110 < 128 cap -> no AGPR tax, 4 waves/EU).
// ---------------------------------------------------------------------------
__global__ __launch_bounds__(THREADS, 4) void disco_fused(
    const float2* __restrict__ xg, const float2* __restrict__ wt2,
    const u32* __restrict__ offsG, const float4* __restrict__ psisG,
    const int* __restrict__ clsOffG, float* __restrict__ out)
{
    int t = blockIdx.x, cg = blockIdx.y, b = blockIdx.z;
    int tid = threadIdx.x;
    int p = tid < NLON ? tid : NLON - 1;
    bool act = tid < NLON;
    const int* co = clsOffG + t * 31;

    float acc[NCH];
#pragma unroll
    for (int o = 0; o < NCH; o++) acc[o] = 0.f;

#pragma clang loop unroll(disable)
    for (int pk = 0; pk < PPB; pk++) {
        int cp2 = cg * PPB + pk;
        const float2* xgb = xg + (size_t)(b * NP2 + cp2) * NLAT * 360;
        const float2* wt2cp = wt2 + (size_t)cp2 * KSZ * NCH;

        float z0[2] = {0.f, 0.f};
        float zA[6][2], zB[6][2];
#pragma unroll
        for (int j = 0; j < 6; j++) {
            zA[j][0] = 0.f; zA[j][1] = 0.f;
            zB[j][0] = 0.f; zB[j][1] = 0.f;
        }

#define SEG(ROW, IP) runSeg2<ROW, IP>(co[(ROW)*6+(IP)], co[(ROW)*6+(IP)+1], \
                                      offsG, psisG, xgb, p, z0, zA, zB)
#define ROW6(ROW) SEG(ROW,0); SEG(ROW,1); SEG(ROW,2); SEG(ROW,3); SEG(ROW,4); SEG(ROW,5)
#define ROLL() { _Pragma("unroll") for (int j = 0; j < 6; j++) { \
                   zA[j][0] = zB[j][0]; zB[j][0] = 0.f; \
                   zA[j][1] = zB[j][1]; zB[j][1] = 0.f; } }

        ROW6(0);
        {   // flush k=0 from z0
            const float2* wk = wt2cp;
#pragma unroll
            for (int o = 0; o < NCH; o++) {
                float2 w2 = wk[o];
                acc[o] = fmaf(w2.y, z0[1], fmaf(w2.x, z0[0], acc[o]));
            }
        }
        ROLL();
        ROW6(1);
        flushRing2(acc, wt2cp, 1, zA);    // k 1..6
        ROLL();
        ROW6(2);
        flushRing2(acc, wt2cp, 7, zA);    // k 7..12
        ROLL();
        ROW6(3);
        flushRing2(acc, wt2cp, 13, zA);   // k 13..18
        ROLL();
        ROW6(4);
        flushRing2(acc, wt2cp, 19, zA);   // k 19..24
#undef SEG
#undef ROW6
#undef ROLL
    }

    if (act) {
        float* op = out + ((size_t)b * NCH * NLAT * NLON) + (size_t)t * NLON + p;
#pragma unroll
        for (int o = 0; o < NCH; o++)
            atomicAdd(op + (size_t)o * (NLAT * NLON), acc[o]);
    }
}

extern "C" void kernel_launch(void* const* d_in, const int* in_sizes, int n_in,
                              void* d_out, int out_size, void* d_ws, size_t ws_size,
                              hipStream_t stream)
{
    const float* x   = (const float*)d_in[0];
    const float* wgt = (const float*)d_in[1];
    char* ws = (char*)d_ws;

    size_t cur = 0;
    auto alloc = [&](size_t bytes) { size_t o = cur; cur = (cur + bytes + 255) & ~(size_t)255; return o; };
    size_t blob_off = alloc(BLOB_MAX);                                // ~1.0 MB
    size_t xd2_off  = alloc((size_t)NB * NP2 * NLAT * 360 * 8);       // 16.8 MB
    size_t wt2_off  = alloc((size_t)NP2 * KSZ * NCH * 8);             // 400 KB

    unsigned char* d_blob = (unsigned char*)(ws + blob_off);
    float2*        xd2    = (float2*)(ws + xd2_off);
    float2*        wt2    = (float2*)(ws + wt2_off);

    hipMemcpyAsync(d_blob, g_init.blob, g_init.bytes, hipMemcpyHostToDevice, stream);
    pack_x2<<<dim3(NLAT, NP2, NB), THREADS, 0, stream>>>(x, xd2);
    pack_w2<<<(NP2 * KSZ * NCH + 255) / 256, 256, 0, stream>>>(wgt, wt2);
    hipMemsetAsync(d_out, 0, (size_t)out_size * 4, stream);

    const u32*    offsD = (const u32*)(d_blob + g_init.offs_off);
    const float4* psisD = (const float4*)(d_blob + PSIS_OFF);
    const int*    clsD  = (const int*)(d_blob + CLS_OFF);

    disco_fused<<<dim3(NLAT, CGRP, NB), THREADS, 0, stream>>>(
        xd2, wt2, offsD, psisD, clsD, (float*)d_out);
}